// Round 6
// baseline (466.687 us; speedup 1.0000x reference)
//
#include <hip/hip_runtime.h>

// LSTM cell fused, round 9: R8's fused single-kernel retried with
// (1) the LDS fragment-base bug FIXED: abase = wm*16384 (half panels are
//     16KB = {ks0 8K, ks1 8K}), bbase = 32768 + (wn>>1)*16384 + (wn&1)*4096
//     -- R8 wrongly used wm*8192 (R7's contiguous layout) -> wm=1/wn>=2
//     waves read wrong panels -> absmax 0.855.
// (2) cooperative launch replaced by a software grid barrier: regular
//     launch, grid=256 (=#CUs, 1 block/CU forced by 128KB LDS => all
//     resident), counter in d_ws zeroed per-iteration via hipMemsetAsync
//     (graph-capturable), __threadfence() both sides for cross-XCD L2.
// Fallback (ws too small): two-kernel path with the same template, PREP=0.

#define BDIM 8192
#define KDIM 2048
#define NDIM 1024
#define NCAT 4096
#define NT   32      // K-tiles of 64

typedef __bf16 bf16x8 __attribute__((ext_vector_type(8)));
typedef float  f32x4  __attribute__((ext_vector_type(4)));

__device__ __forceinline__ void async_cp16(const void* g, void* l) {
    __builtin_amdgcn_global_load_lds((__attribute__((address_space(1))) void*)g,
                                     (__attribute__((address_space(3))) void*)l,
                                     16, 0, 0);
}

__device__ __forceinline__ float sigm(float x) { return 1.f / (1.f + __expf(-x)); }
__device__ __forceinline__ float tanh_fast(float x) { return 1.f - 2.f / (1.f + __expf(2.f * x)); }

#define BARM asm volatile("s_barrier" ::: "memory")

// ---------------- fallback prep (R6-proven) ----------------
__global__ __launch_bounds__(256)
void prep_kernel(const float* __restrict__ Z, const float* __restrict__ H,
                 const float* __restrict__ Wi, const float* __restrict__ Wf,
                 const float* __restrict__ Wo, const float* __restrict__ Wg,
                 __bf16* __restrict__ A, __bf16* __restrict__ Wt) {
    __shared__ float t[64][65];
    const int bid = blockIdx.x;
    const int tid = threadIdx.x;

    if (bid < 8192) {
        const bool isZ = (bid < 4096);
        const int idx  = (isZ ? bid : bid - 4096) * 256 + tid;
        const int row  = idx >> 7;
        const int q8   = idx & 127;
        const float* src = isZ ? Z : H;
        const float4* p = (const float4*)src + ((size_t)row << 8) + q8 * 2;
        float4 v0 = p[0], v1 = p[1];
        bf16x8 o = { (__bf16)v0.x, (__bf16)v0.y, (__bf16)v0.z, (__bf16)v0.w,
                     (__bf16)v1.x, (__bf16)v1.y, (__bf16)v1.z, (__bf16)v1.w };
        const int col8 = isZ ? q8 : (q8 + 128);
        ((bf16x8*)A)[(size_t)row * 256 + col8] = o;
    } else {
        const int id  = bid - 8192;
        const int g   = id >> 9;
        const int rem = id & 511;
        const int k0  = (rem & 31) * 64;
        const int n0  = (rem >> 5) * 64;
        const float* W = (g == 0) ? Wi : (g == 1) ? Wf : (g == 2) ? Wo : Wg;

        const int c4 = tid & 15, r0 = tid >> 4;
        #pragma unroll
        for (int it = 0; it < 4; ++it) {
            const int r = r0 + it * 16;
            float4 v = ((const float4*)W)[(size_t)(k0 + r) * 256 + (n0 >> 2) + c4];
            t[r][c4 * 4 + 0] = v.x;
            t[r][c4 * 4 + 1] = v.y;
            t[r][c4 * 4 + 2] = v.z;
            t[r][c4 * 4 + 3] = v.w;
        }
        __syncthreads();

        const int kc = tid & 7, nn0 = tid >> 3;
        #pragma unroll
        for (int j = 0; j < 2; ++j) {
            const int n    = nn0 + j * 32;
            const int ncat = n0 + n;
            const size_t outRow = (size_t)(ncat >> 5) * 128 + g * 32 + (ncat & 31);
            bf16x8 o;
            #pragma unroll
            for (int kk = 0; kk < 8; ++kk) o[kk] = (__bf16)t[kc * 8 + kk][n];
            *(bf16x8*)(Wt + outRow * KDIM + k0 + kc * 8) = o;
        }
    }
}

// ---------------- fused kernel: [prep + grid-barrier +] two-tile GEMM ------
template<bool PREP>
__global__ __launch_bounds__(512, 2)
void fused_lstm(const float* __restrict__ Z, const float* __restrict__ H,
                const float* __restrict__ c_prev,
                const float* __restrict__ Wi, const float* __restrict__ Wf,
                const float* __restrict__ Wo, const float* __restrict__ Wg,
                const float* __restrict__ b_i, const float* __restrict__ b_f,
                const float* __restrict__ b_o, const float* __restrict__ b_g,
                __bf16* __restrict__ A, __bf16* __restrict__ Wt,
                unsigned* __restrict__ bar, float* __restrict__ out) {
    extern __shared__ char smem[];   // 128 KB dynamic

    const int tid = threadIdx.x;
    const int bid = blockIdx.x;      // 0..255, one block per CU

    if constexpr (PREP) {
        // ---- A pack: 16 bf16x8 units per thread ----
        const int gtid = bid * 512 + tid;            // 0..131071
        #pragma unroll
        for (int t = 0; t < 16; ++t) {
            const int u    = gtid + t * 131072;
            const int row  = u >> 8;
            const int col8 = u & 255;
            const float* src = (col8 < 128) ? Z : H;
            const int q8 = col8 & 127;
            const float4* p = (const float4*)src + ((size_t)row << 8) + q8 * 2;
            float4 v0 = p[0], v1 = p[1];
            bf16x8 o = { (__bf16)v0.x, (__bf16)v0.y, (__bf16)v0.z, (__bf16)v0.w,
                         (__bf16)v1.x, (__bf16)v1.y, (__bf16)v1.z, (__bf16)v1.w };
            ((bf16x8*)A)[(size_t)row * 256 + col8] = o;
        }

        // ---- W transpose: 8 64x64 tiles per block ----
        float* tt = (float*)smem;                    // [64][65] f32 overlay
        const int c4 = tid & 15, r0 = tid >> 4;
        const int kc = tid & 7,  nn2 = tid >> 3;
        #pragma unroll 1
        for (int it = 0; it < 8; ++it) {
            const int id  = bid * 8 + it;            // 0..2047
            const int g   = id >> 9;
            const int rem = id & 511;
            const int k0  = (rem & 31) * 64;
            const int n0t = (rem >> 5) * 64;
            const float* W = (g == 0) ? Wi : (g == 1) ? Wf : (g == 2) ? Wo : Wg;
            __syncthreads();
            #pragma unroll
            for (int j = 0; j < 2; ++j) {
                const int r = r0 + j * 32;
                float4 v = ((const float4*)W)[(size_t)(k0 + r) * 256 + (n0t >> 2) + c4];
                tt[r * 65 + c4 * 4 + 0] = v.x;
                tt[r * 65 + c4 * 4 + 1] = v.y;
                tt[r * 65 + c4 * 4 + 2] = v.z;
                tt[r * 65 + c4 * 4 + 3] = v.w;
            }
            __syncthreads();
            const int ncat = n0t + nn2;
            const size_t outRow = (size_t)(ncat >> 5) * 128 + g * 32 + (ncat & 31);
            bf16x8 o;
            #pragma unroll
            for (int kk = 0; kk < 8; ++kk) o[kk] = (__bf16)tt[(kc * 8 + kk) * 65 + nn2];
            *(bf16x8*)(Wt + outRow * KDIM + k0 + kc * 8) = o;
        }

        // ---- software grid barrier (all 256 blocks resident: 1/CU) ----
        __syncthreads();
        __threadfence();             // publish A/Wt (L2 wb across XCDs)
        if (tid == 0) {
            atomicAdd(bar, 1u);
            while (atomicAdd(bar, 0u) < 256u) __builtin_amdgcn_s_sleep(2);
        }
        __syncthreads();
        __threadfence();             // invalidate stale L1/L2 lines
    }

    // ================= GEMM: two 256x256 tiles per block =================
    const int wave = tid >> 6;
    const int lane = tid & 63;
    const int wm   = wave >> 2;      // m half (128 rows)
    const int wn   = wave & 3;       // 64 cat cols
    const int l15  = lane & 15;
    const int quad = lane >> 4;

    const int xcd = bid & 7;
    const int j   = bid >> 3;                 // 0..31
    const int bxc = xcd * 2 + (j & 1);        // cat-tile [0,16)
    const int by0 = j >> 1;                   // m-tile   [0,16)
    const int m0a  = by0 * 256;
    const int m0b  = m0a + 4096;
    const int cat0 = bxc * 256;
    const int n0c  = bxc * 64;

    const int srow = tid >> 2;
    const int sgch = (tid & 3) ^ ((tid >> 3) & 3);
    const __bf16* AgsA = A  + (size_t)(m0a  + srow) * KDIM + sgch * 8;
    const __bf16* AgsB = AgsA + (size_t)4096 * KDIM;
    const __bf16* Bgs  = Wt + (size_t)(cat0 + srow) * KDIM + sgch * 8;
    char* ldsw = smem + wave * 1024;

#define STG(AP, o, h, kt, b) do { \
    const __bf16* gp_ = ((o) ? Bgs : (AP)) + (size_t)(h) * 128 * KDIM + (kt) * 64; \
    char* lp_ = ldsw + (b) * 65536 + (o) * 32768 + (h) * 16384; \
    async_cp16(gp_,      lp_); \
    async_cp16(gp_ + 32, lp_ + 8192); \
} while (0)

    // R6-correct bases: half panels are 16KB apart ({ks0 8K | ks1 8K})
    const int swz   = (quad ^ ((l15 >> 1) & 3)) * 16;
    const int abase = wm * 16384 + l15 * 64 + swz;
    const int bbase = 32768 + (wn >> 1) * 16384 + (wn & 1) * 4096 + l15 * 64 + swz;

    f32x4 acc[8][4];
    bf16x8 afr[4][2];
    bf16x8 bfr[4][2];

    auto LDA = [&](int mh, int bufb) {
        const char* p = smem + bufb + abase + mh * 4096;
        #pragma unroll
        for (int m = 0; m < 4; ++m) {
            afr[m][0] = *(const bf16x8*)(p + m * 1024);
            afr[m][1] = *(const bf16x8*)(p + m * 1024 + 8192);
        }
    };
    auto LDB = [&](int nh, int bufb) {
        const char* p = smem + bufb + bbase + nh * 2048;
        #pragma unroll
        for (int n = 0; n < 2; ++n) {
            bfr[nh * 2 + n][0] = *(const bf16x8*)(p + n * 1024);
            bfr[nh * 2 + n][1] = *(const bf16x8*)(p + n * 1024 + 8192);
        }
    };
    auto MMA = [&](int mh, int nh) {
        #pragma unroll
        for (int m = 0; m < 4; ++m)
            #pragma unroll
            for (int n = 0; n < 2; ++n) {
                acc[mh * 4 + m][nh * 2 + n] = __builtin_amdgcn_mfma_f32_16x16x32_bf16(
                    afr[m][0], bfr[nh * 2 + n][0], acc[mh * 4 + m][nh * 2 + n], 0, 0, 0);
                acc[mh * 4 + m][nh * 2 + n] = __builtin_amdgcn_mfma_f32_16x16x32_bf16(
                    afr[m][1], bfr[nh * 2 + n][1], acc[mh * 4 + m][nh * 2 + n], 0, 0, 0);
            }
    };

#define ZERO_ACC do { \
    _Pragma("unroll") \
    for (int i = 0; i < 8; ++i) \
        _Pragma("unroll") \
        for (int jj = 0; jj < 4; ++jj) acc[i][jj] = (f32x4){0.f, 0.f, 0.f, 0.f}; \
} while (0)

#define KLOOP(AP) do { \
    _Pragma("unroll 2") \
    for (int t = 0; t < NT; ++t) { \
        const int b    = t & 1; \
        const int bufb = b * 65536; \
        LDA(0, bufb); LDB(0, bufb); \
        if (t + 1 < NT) STG(AP, 0, 1, t + 1, b ^ 1); \
        BARM; asm volatile("s_waitcnt lgkmcnt(0)" ::: "memory"); \
        __builtin_amdgcn_s_setprio(1); MMA(0, 0); __builtin_amdgcn_s_setprio(0); \
        BARM; \
        LDB(1, bufb); \
        if (t + 1 < NT) STG(AP, 1, 1, t + 1, b ^ 1); \
        BARM; asm volatile("s_waitcnt lgkmcnt(0)" ::: "memory"); \
        __builtin_amdgcn_s_setprio(1); MMA(0, 1); __builtin_amdgcn_s_setprio(0); \
        BARM; \
        LDA(1, bufb); \
        BARM; asm volatile("s_waitcnt lgkmcnt(0)" ::: "memory"); \
        __builtin_amdgcn_s_setprio(1); MMA(1, 0); __builtin_amdgcn_s_setprio(0); \
        BARM; \
        if (t + 2 < NT) { STG(AP, 0, 0, t + 2, b); STG(AP, 1, 0, t + 2, b); } \
        if (t < NT - 2) { asm volatile("s_waitcnt vmcnt(4)" ::: "memory"); } \
        else            { asm volatile("s_waitcnt vmcnt(0)" ::: "memory"); } \
        BARM; \
        __builtin_amdgcn_s_setprio(1); MMA(1, 1); __builtin_amdgcn_s_setprio(0); \
        BARM; \
    } \
} while (0)

    const int nn = tid & 63;
    const float bvi = b_i[n0c + nn], bvf = b_f[n0c + nn];
    const float bvo = b_o[n0c + nn], bvg = b_g[n0c + nn];
    int colW[4];
    #pragma unroll
    for (int nt = 0; nt < 4; ++nt)
        colW[nt] = ((wn & 1) * 2 + (nt >> 1)) * 64 + (wn >> 1) * 32 + (nt & 1) * 16 + l15;

#define EPI(m0v) do { \
    float* Ep = (float*)(smem + 94208); \
    _Pragma("unroll 1") \
    for (int ch = 0; ch < 8; ++ch) { \
        __syncthreads(); \
        if (wm == (ch >> 2)) { \
            _Pragma("unroll") \
            for (int mi2 = 0; mi2 < 2; ++mi2) { \
                const int mt = (ch & 3) * 2 + mi2; \
                _Pragma("unroll") \
                for (int nt = 0; nt < 4; ++nt) \
                    _Pragma("unroll") \
                    for (int r = 0; r < 4; ++r) \
                        Ep[(mi2 * 16 + quad * 4 + r) * 258 + colW[nt]] = acc[mt][nt][r]; \
            } \
        } \
        __syncthreads(); \
        _Pragma("unroll") \
        for (int e = 0; e < 4; ++e) { \
            const int idx = tid + e * 512; \
            const int row = idx >> 6; \
            const float gi = sigm(Ep[row * 258 + nn] + bvi); \
            const float gf = sigm(Ep[row * 258 + 64 + nn] + bvf); \
            const float go = sigm(Ep[row * 258 + 128 + nn] + bvo); \
            const float gg = tanh_fast(Ep[row * 258 + 192 + nn] + bvg); \
            const size_t pos = (size_t)((m0v) + ch * 32 + row) * NDIM + n0c + nn; \
            const float cp = c_prev[pos]; \
            const float cv = gf * cp + gi * gg; \
            out[pos] = go * tanh_fast(cv); \
            out[(size_t)BDIM * NDIM + pos] = cv; \
        } \
    } \
} while (0)

    // ---- tile 0 ----
    ZERO_ACC;
    STG(AgsA, 0, 0, 0, 0); STG(AgsA, 1, 0, 0, 0);
    STG(AgsA, 0, 1, 0, 0); STG(AgsA, 1, 1, 0, 0);
    STG(AgsA, 0, 0, 1, 1); STG(AgsA, 1, 0, 1, 1);
    asm volatile("s_waitcnt vmcnt(4)" ::: "memory");
    BARM;
    KLOOP(AgsA);

    // prefetch tile1 K-tile0 into buf0 -- flies under tile0's epilogue
    STG(AgsB, 0, 0, 0, 0); STG(AgsB, 1, 0, 0, 0);
    STG(AgsB, 0, 1, 0, 0); STG(AgsB, 1, 1, 0, 0);

    EPI(m0a);
    __syncthreads();   // Ep reads done before buf1-B staging overwrites it

    // ---- tile 1 ----
    ZERO_ACC;
    STG(AgsB, 0, 0, 1, 1); STG(AgsB, 1, 0, 1, 1);
    asm volatile("s_waitcnt vmcnt(4)" ::: "memory");
    BARM;
    KLOOP(AgsB);
    EPI(m0b);

#undef STG
#undef KLOOP
#undef EPI
#undef ZERO_ACC
}

extern "C" void kernel_launch(void* const* d_in, const int* in_sizes, int n_in,
                              void* d_out, int out_size, void* d_ws, size_t ws_size,
                              hipStream_t stream) {
    const float* Z  = (const float*)d_in[0];
    const float* H  = (const float*)d_in[1];
    const float* Cp = (const float*)d_in[2];
    const float* Wi = (const float*)d_in[3];
    const float* bi = (const float*)d_in[4];
    const float* Wf = (const float*)d_in[5];
    const float* bf = (const float*)d_in[6];
    const float* Wo = (const float*)d_in[7];
    const float* bo = (const float*)d_in[8];
    const float* Wg = (const float*)d_in[9];
    const float* bg = (const float*)d_in[10];
    float* outp = (float*)d_out;

    static bool cfg = false;
    if (!cfg) {
        hipFuncSetAttribute(reinterpret_cast<const void*>(fused_lstm<true>),
                            hipFuncAttributeMaxDynamicSharedMemorySize, 131072);
        hipFuncSetAttribute(reinterpret_cast<const void*>(fused_lstm<false>),
                            hipFuncAttributeMaxDynamicSharedMemorySize, 131072);
        cfg = true;
    }

    const size_t need = (size_t)4096 + 33554432 + 16777216;   // bar pad + A + Wt
    if (ws_size >= need) {
        unsigned* bar = (unsigned*)d_ws;
        __bf16* Acomb = (__bf16*)((char*)d_ws + 4096);
        __bf16* Wtp   = (__bf16*)((char*)d_ws + 4096 + (size_t)33554432);
        hipMemsetAsync(d_ws, 0, 64, stream);
        fused_lstm<true><<<256, 512, 131072, stream>>>(
            Z, H, Cp, Wi, Wf, Wo, Wg, bi, bf, bo, bg, Acomb, Wtp, bar, outp);
    } else {
        __bf16* Acomb = (__bf16*)d_ws;
        __bf16* Wtp   = (__bf16*)((char*)d_ws + (size_t)33554432);
        prep_kernel<<<10240, 256, 0, stream>>>(Z, H, Wi, Wf, Wo, Wg, Acomb, Wtp);
        fused_lstm<false><<<256, 512, 131072, stream>>>(
            Z, H, Cp, Wi, Wf, Wo, Wg, bi, bf, bo, bg, Acomb, Wtp, nullptr, outp);
    }
}

// Round 8
// 387.540 us; speedup vs baseline: 1.2042x; 1.2042x over previous
//
#include <hip/hip_runtime.h>

// LSTM cell fused, round 11: R10's 32x32x16 GEMM with the B-fragment
// lifetime bug FIXED. R10 held only one nh's B-frags (bfr[4]) but the phase
// order (0,0),(0,1),(1,0),(1,1) reuses nh=0 at phase 2 -> MMA(1,0) consumed
// nh=1 data -> absmax 0.67. Fix: bfr[2][4], both nh halves live (R6's
// invariant). All addressing identical to R10 (re-derived & self-checked):
// staging/swizzle byte-identical to R6-proven layout; A/B k-mapping
// permutation-consistent; C/D per m74/m101 col=lane&31,
// row=(reg&3)+8*(reg>>2)+4*(lane>>5).

#define BDIM 8192
#define KDIM 2048
#define NDIM 1024
#define NCAT 4096
#define NT   32      // K-tiles of 64

typedef __bf16 bf16x8 __attribute__((ext_vector_type(8)));
typedef float  f32x4  __attribute__((ext_vector_type(4)));
typedef float  f32x16 __attribute__((ext_vector_type(16)));

__device__ __forceinline__ void async_cp16(const void* g, void* l) {
    __builtin_amdgcn_global_load_lds((__attribute__((address_space(1))) void*)g,
                                     (__attribute__((address_space(3))) void*)l,
                                     16, 0, 0);
}

__device__ __forceinline__ float sigm(float x) { return 1.f / (1.f + __expf(-x)); }
__device__ __forceinline__ float tanh_fast(float x) { return 1.f - 2.f / (1.f + __expf(2.f * x)); }

#define BARM asm volatile("s_barrier" ::: "memory")

// ---------------- prep: A pack + weight transpose (R6-proven) ----------------
__global__ __launch_bounds__(256)
void prep_kernel(const float* __restrict__ Z, const float* __restrict__ H,
                 const float* __restrict__ Wi, const float* __restrict__ Wf,
                 const float* __restrict__ Wo, const float* __restrict__ Wg,
                 __bf16* __restrict__ A, __bf16* __restrict__ Wt) {
    __shared__ float t[64][65];
    const int bid = blockIdx.x;
    const int tid = threadIdx.x;

    if (bid < 8192) {
        const bool isZ = (bid < 4096);
        const int idx  = (isZ ? bid : bid - 4096) * 256 + tid;
        const int row  = idx >> 7;
        const int q8   = idx & 127;
        const float* src = isZ ? Z : H;
        const float4* p = (const float4*)src + ((size_t)row << 8) + q8 * 2;
        float4 v0 = p[0], v1 = p[1];
        bf16x8 o = { (__bf16)v0.x, (__bf16)v0.y, (__bf16)v0.z, (__bf16)v0.w,
                     (__bf16)v1.x, (__bf16)v1.y, (__bf16)v1.z, (__bf16)v1.w };
        const int col8 = isZ ? q8 : (q8 + 128);
        ((bf16x8*)A)[(size_t)row * 256 + col8] = o;
    } else {
        const int id  = bid - 8192;
        const int g   = id >> 9;
        const int rem = id & 511;
        const int k0  = (rem & 31) * 64;
        const int n0  = (rem >> 5) * 64;
        const float* W = (g == 0) ? Wi : (g == 1) ? Wf : (g == 2) ? Wo : Wg;

        const int c4 = tid & 15, r0 = tid >> 4;
        #pragma unroll
        for (int it = 0; it < 4; ++it) {
            const int r = r0 + it * 16;
            float4 v = ((const float4*)W)[(size_t)(k0 + r) * 256 + (n0 >> 2) + c4];
            t[r][c4 * 4 + 0] = v.x;
            t[r][c4 * 4 + 1] = v.y;
            t[r][c4 * 4 + 2] = v.z;
            t[r][c4 * 4 + 3] = v.w;
        }
        __syncthreads();

        const int kc = tid & 7, nn0 = tid >> 3;
        #pragma unroll
        for (int j = 0; j < 2; ++j) {
            const int n    = nn0 + j * 32;
            const int ncat = n0 + n;
            const size_t outRow = (size_t)(ncat >> 5) * 128 + g * 32 + (ncat & 31);
            bf16x8 o;
            #pragma unroll
            for (int kk = 0; kk < 8; ++kk) o[kk] = (__bf16)t[kc * 8 + kk][n];
            *(bf16x8*)(Wt + outRow * KDIM + k0 + kc * 8) = o;
        }
    }
}

// ---------------- 256x256 GEMM (32x32x16 MFMA) + fused LSTM epilogue --------
__global__ __launch_bounds__(512, 2)
void lstm_gemm_kernel(const __bf16* __restrict__ A, const __bf16* __restrict__ Wt,
                      const float* __restrict__ b_i, const float* __restrict__ b_f,
                      const float* __restrict__ b_o, const float* __restrict__ b_g,
                      const float* __restrict__ c_prev, float* __restrict__ out) {
    extern __shared__ char smem[];   // 128KB: buf{0,1} x { A 2x16KB | B 2x16KB }

    const int tid  = threadIdx.x;
    const int wave = tid >> 6;
    const int lane = tid & 63;
    const int wm   = wave >> 2;      // m half (128 rows)
    const int wn   = wave & 3;       // 64 cat cols
    const int l31  = lane & 31;
    const int lh   = lane >> 5;      // k-group within instruction

    // XCD swizzle (R6): 512 blocks, 8 XCDs -> 2 cat-panels x 32 by each
    const int bid = blockIdx.x;
    const int bxc = (bid & 7) * 2 + (bid >> 8);   // cat-tile [0,16)
    const int by  = (bid >> 3) & 31;              // m-tile   [0,32)
    const int m0   = by * 256;
    const int cat0 = bxc * 256;
    const int n0c  = bxc * 64;

    // staging identical to R6 (0-conflict proven): lds linear, global chunk
    // pre-swizzled (tid&3)^((tid>>3)&3)
    const int srow = tid >> 2;
    const int sgch = (tid & 3) ^ ((tid >> 3) & 3);
    const __bf16* Ags = A  + (size_t)(m0   + srow) * KDIM + sgch * 8;
    const __bf16* Bgs = Wt + (size_t)(cat0 + srow) * KDIM + sgch * 8;
    char* ldsw = smem + wave * 1024;

#define STG(o, h, kt, b) do { \
    const __bf16* gp_ = ((o) ? Bgs : Ags) + (size_t)(h) * 128 * KDIM + (kt) * 64; \
    char* lp_ = ldsw + (b) * 65536 + (o) * 32768 + (h) * 16384; \
    async_cp16(gp_,      lp_); \
    async_cp16(gp_ + 32, lp_ + 8192); \
} while (0)

    // fragment addressing for 32x32x16: row = sub*32 + l31 (64B rows),
    // k-inst ki in [0,4): panel ks=ki>>1 (+8192), local chunk 2*(ki&1)+lh,
    // stored chunk = local ^ ((row>>1)&3); (row>>1)&3 == (lane>>1)&3 here.
    const int rowb = l31 * 64;
    int achk[4];
    #pragma unroll
    for (int ki = 0; ki < 4; ++ki)
        achk[ki] = (ki >> 1) * 8192 + (((2 * (ki & 1) + lh) ^ ((lane >> 1) & 3)) * 16);
    const int abase = wm * 16384 + rowb;                                  // + mh*4096 + mi*2048
    const int bbase = 32768 + (wn >> 1) * 16384 + (wn & 1) * 4096 + rowb; // + nh*2048

    f32x16 acc[4][2];
    #pragma unroll
    for (int i = 0; i < 4; ++i)
        #pragma unroll
        for (int j = 0; j < 2; ++j)
            #pragma unroll
            for (int r = 0; r < 16; ++r) acc[i][j][r] = 0.f;

    bf16x8 af[2][4];    // 2 m-subtiles x 4 k-insts for CURRENT mh
    bf16x8 bfr[2][4];   // BOTH nh halves live x 4 k-insts  (R10 bug fix)

    auto LDA = [&](int mh, int bufb) {
        const char* p = smem + bufb + abase + mh * 4096;
        #pragma unroll
        for (int mi = 0; mi < 2; ++mi)
            #pragma unroll
            for (int ki = 0; ki < 4; ++ki)
                af[mi][ki] = *(const bf16x8*)(p + mi * 2048 + achk[ki]);
    };
    auto LDB = [&](int nh, int bufb) {
        const char* p = smem + bufb + bbase + nh * 2048;
        #pragma unroll
        for (int ki = 0; ki < 4; ++ki)
            bfr[nh][ki] = *(const bf16x8*)(p + achk[ki]);
    };
    auto MMA = [&](int mh, int nh) {
        #pragma unroll
        for (int ki = 0; ki < 4; ++ki)
            #pragma unroll
            for (int mi = 0; mi < 2; ++mi)
                acc[mh * 2 + mi][nh] = __builtin_amdgcn_mfma_f32_32x32x16_bf16(
                    af[mi][ki], bfr[nh][ki], acc[mh * 2 + mi][nh], 0, 0, 0);
    };

    // ---- prologue: tile0 fully + tile1 h0 halves (4 loads stay in flight)
    STG(0, 0, 0, 0); STG(1, 0, 0, 0); STG(0, 1, 0, 0); STG(1, 1, 0, 0);
    STG(0, 0, 1, 1); STG(1, 0, 1, 1);
    asm volatile("s_waitcnt vmcnt(4)" ::: "memory");
    BARM;

    #pragma unroll 2
    for (int t = 0; t < NT; ++t) {
        const int b    = t & 1;
        const int bufb = b * 65536;
        // phase 0: (mh0, nh0); stage (t+1) A-h1
        LDA(0, bufb); LDB(0, bufb);
        if (t + 1 < NT) STG(0, 1, t + 1, b ^ 1);
        BARM; asm volatile("s_waitcnt lgkmcnt(0)" ::: "memory");
        __builtin_amdgcn_s_setprio(1); MMA(0, 0); __builtin_amdgcn_s_setprio(0);
        BARM;
        // phase 1: (mh0, nh1); stage (t+1) B-h1
        LDB(1, bufb);
        if (t + 1 < NT) STG(1, 1, t + 1, b ^ 1);
        BARM; asm volatile("s_waitcnt lgkmcnt(0)" ::: "memory");
        __builtin_amdgcn_s_setprio(1); MMA(0, 1); __builtin_amdgcn_s_setprio(0);
        BARM;
        // phase 2: (mh1, nh0) -- bfr[0] still holds nh=0 (fix)
        LDA(1, bufb);
        BARM; asm volatile("s_waitcnt lgkmcnt(0)" ::: "memory");
        __builtin_amdgcn_s_setprio(1); MMA(1, 0); __builtin_amdgcn_s_setprio(0);
        BARM;
        // phase 3: (mh1, nh1); stage (t+2) h0 halves; counted vmcnt publishes t+1
        if (t + 2 < NT) { STG(0, 0, t + 2, b); STG(1, 0, t + 2, b); }
        if (t < NT - 2) { asm volatile("s_waitcnt vmcnt(4)" ::: "memory"); }
        else            { asm volatile("s_waitcnt vmcnt(0)" ::: "memory"); }
        BARM;
        __builtin_amdgcn_s_setprio(1); MMA(1, 1); __builtin_amdgcn_s_setprio(0);
        BARM;
    }

    // ---- epilogue: 8 chunks of 32 rows; Ep[32][258] f32 at smem base ----
    // C/D: col = l31, row-in-subtile = (r&3) + 8*(r>>2) + 4*lh  [m74/m101]
    // cat_local = wn*64 + nt*32 + l31 -> q = 2wn+nt: gate = q&3,
    // n_rel = (q>>2)*32 + l31
    float* Ep = (float*)smem;
    const int nn = tid & 63;
    const float bvi = b_i[n0c + nn], bvf = b_f[n0c + nn];
    const float bvo = b_o[n0c + nn], bvg = b_g[n0c + nn];
    int colW[2];
    #pragma unroll
    for (int nt = 0; nt < 2; ++nt) {
        const int q = 2 * wn + nt;
        colW[nt] = ((q & 3) << 6) + ((q >> 2) << 5) + l31;
    }

    #pragma unroll 1
    for (int ch = 0; ch < 8; ++ch) {
        __syncthreads();
        if (wm == (ch >> 2)) {
            const int mt = ch & 3;
            #pragma unroll
            for (int nt = 0; nt < 2; ++nt)
                #pragma unroll
                for (int r = 0; r < 16; ++r)
                    Ep[((r & 3) + ((r >> 2) << 3) + (lh << 2)) * 258 + colW[nt]] =
                        acc[mt][nt][r];
        }
        __syncthreads();
        #pragma unroll
        for (int e = 0; e < 4; ++e) {
            const int idx = tid + e * 512;
            const int row = idx >> 6;
            const float gi = sigm(Ep[row * 258 + nn] + bvi);
            const float gf = sigm(Ep[row * 258 + 64 + nn] + bvf);
            const float go = sigm(Ep[row * 258 + 128 + nn] + bvo);
            const float gg = tanh_fast(Ep[row * 258 + 192 + nn] + bvg);
            const size_t pos = (size_t)(m0 + ch * 32 + row) * NDIM + n0c + nn;
            const float cp = c_prev[pos];
            const float cv = gf * cp + gi * gg;
            out[pos] = go * tanh_fast(cv);                 // h
            out[(size_t)BDIM * NDIM + pos] = cv;           // c
        }
    }
#undef STG
}

extern "C" void kernel_launch(void* const* d_in, const int* in_sizes, int n_in,
                              void* d_out, int out_size, void* d_ws, size_t ws_size,
                              hipStream_t stream) {
    const float* Z  = (const float*)d_in[0];
    const float* H  = (const float*)d_in[1];
    const float* Cp = (const float*)d_in[2];
    const float* Wi = (const float*)d_in[3];
    const float* bi = (const float*)d_in[4];
    const float* Wf = (const float*)d_in[5];
    const float* bf = (const float*)d_in[6];
    const float* Wo = (const float*)d_in[7];
    const float* bo = (const float*)d_in[8];
    const float* Wg = (const float*)d_in[9];
    const float* bg = (const float*)d_in[10];

    __bf16* Acomb = (__bf16*)d_ws;                              // 32 MB
    __bf16* Wtp   = (__bf16*)((char*)d_ws + (size_t)33554432);  // 16 MB

    static bool cfg = false;
    if (!cfg) {
        hipFuncSetAttribute(reinterpret_cast<const void*>(lstm_gemm_kernel),
                            hipFuncAttributeMaxDynamicSharedMemorySize, 131072);
        cfg = true;
    }

    prep_kernel<<<10240, 256, 0, stream>>>(Z, H, Wi, Wf, Wo, Wg, Acomb, Wtp);
    lstm_gemm_kernel<<<512, 512, 131072, stream>>>(
        Acomb, Wtp, bi, bf, bo, bg, Cp, (float*)d_out);
}

// Round 9
// 316.244 us; speedup vs baseline: 1.4757x; 1.2254x over previous
//
#include <hip/hip_runtime.h>

// LSTM cell fused, round 12: revert GEMM to the R6 kernel byte-for-byte
// (best measured: 163.6us gemm / 319.7 total; the 32x32x16 attempt spilled
// ~260MB of scratch + 1.26e7 bank conflicts -> 246us, refuted).
// Prep restructured: 4096 blocks (was 10240) -- transpose tiles FIRST
// (heaviest per block, no tail), pack 4 units/thread with Z/H in disjoint
// block ranges (128B read / 64B write per thread, 1KB/wave stores).

#define BDIM 8192
#define KDIM 2048
#define NDIM 1024
#define NCAT 4096
#define NT   32      // K-tiles of 64

typedef __bf16 bf16x8 __attribute__((ext_vector_type(8)));
typedef float  f32x4  __attribute__((ext_vector_type(4)));

__device__ __forceinline__ void async_cp16(const void* g, void* l) {
    __builtin_amdgcn_global_load_lds((__attribute__((address_space(1))) void*)g,
                                     (__attribute__((address_space(3))) void*)l,
                                     16, 0, 0);
}

__device__ __forceinline__ float sigm(float x) { return 1.f / (1.f + __expf(-x)); }
__device__ __forceinline__ float tanh_fast(float x) { return 1.f - 2.f / (1.f + __expf(2.f * x)); }

#define BARM asm volatile("s_barrier" ::: "memory")

// ---------------- prep v3: transpose-first, fat pack blocks ----------------
// blocks [0, 2048):    W transpose, 64x64 f32 tile -> Wt bf16 (heavy, first)
// blocks [2048, 3072): Z pack, 4 bf16x8 units/thread
// blocks [3072, 4096): H pack, 4 bf16x8 units/thread
__global__ __launch_bounds__(256)
void prep_kernel(const float* __restrict__ Z, const float* __restrict__ H,
                 const float* __restrict__ Wi, const float* __restrict__ Wf,
                 const float* __restrict__ Wo, const float* __restrict__ Wg,
                 __bf16* __restrict__ A, __bf16* __restrict__ Wt) {
    __shared__ float t[64][65];
    const int bid = blockIdx.x;
    const int tid = threadIdx.x;

    if (bid < 2048) {
        // ---- transpose: gate g, 64(k) x 64(n) tile ----
        const int g   = bid >> 9;
        const int rem = bid & 511;
        const int k0  = (rem & 31) * 64;
        const int n0  = (rem >> 5) * 64;
        const float* W = (g == 0) ? Wi : (g == 1) ? Wf : (g == 2) ? Wo : Wg;

        const int c4 = tid & 15, r0 = tid >> 4;
        #pragma unroll
        for (int it = 0; it < 4; ++it) {
            const int r = r0 + it * 16;
            float4 v = ((const float4*)W)[(size_t)(k0 + r) * 256 + (n0 >> 2) + c4];
            t[r][c4 * 4 + 0] = v.x;
            t[r][c4 * 4 + 1] = v.y;
            t[r][c4 * 4 + 2] = v.z;
            t[r][c4 * 4 + 3] = v.w;
        }
        __syncthreads();

        const int kc = tid & 7, nn0 = tid >> 3;
        #pragma unroll
        for (int j = 0; j < 2; ++j) {
            const int n    = nn0 + j * 32;
            const int ncat = n0 + n;
            const size_t outRow = (size_t)(ncat >> 5) * 128 + g * 32 + (ncat & 31);
            bf16x8 o;
            #pragma unroll
            for (int kk = 0; kk < 8; ++kk) o[kk] = (__bf16)t[kc * 8 + kk][n];
            *(bf16x8*)(Wt + outRow * KDIM + k0 + kc * 8) = o;
        }
    } else {
        // ---- pack: 4 units of {2x float4 -> bf16x8} per thread ----
        const bool isZ = (bid < 3072);
        const int base = (bid - (isZ ? 2048 : 3072)) * 1024;
        const float* src = isZ ? Z : H;
        #pragma unroll
        for (int it = 0; it < 4; ++it) {
            const int u   = base + it * 256 + tid;
            const int row = u >> 7;
            const int q8  = u & 127;
            const float4* p = (const float4*)src + ((size_t)row << 8) + q8 * 2;
            float4 v0 = p[0], v1 = p[1];
            bf16x8 o = { (__bf16)v0.x, (__bf16)v0.y, (__bf16)v0.z, (__bf16)v0.w,
                         (__bf16)v1.x, (__bf16)v1.y, (__bf16)v1.z, (__bf16)v1.w };
            const int col8 = isZ ? q8 : (q8 + 128);
            ((bf16x8*)A)[(size_t)row * 256 + col8] = o;
        }
    }
}

// ---------------- 256x256 8-phase GEMM + fused LSTM epilogue (R6 exact) ----
// LDS per buffer (64KB): A half h at h*16384 = { panel ks0 [128][32] 8KB,
// panel ks1 at +8192 }; B at +32768 likewise. Panel byte addr:
// row*64 + (chunk ^ ((row>>1)&3))*16  -- round-3 proven 0-conflict.
__global__ __launch_bounds__(512, 2)
void lstm_gemm_kernel(const __bf16* __restrict__ A, const __bf16* __restrict__ Wt,
                      const float* __restrict__ b_i, const float* __restrict__ b_f,
                      const float* __restrict__ b_o, const float* __restrict__ b_g,
                      const float* __restrict__ c_prev, float* __restrict__ out) {
    extern __shared__ char smem[];   // 128KB: buf{0,1} x { A 2x16KB | B 2x16KB }

    const int tid  = threadIdx.x;
    const int wave = tid >> 6;
    const int lane = tid & 63;
    const int wm   = wave >> 2;      // 0..1  (m half: 128 rows each)
    const int wn   = wave & 3;       // 0..3  (64 cat cols each)
    const int l15  = lane & 15;
    const int quad = lane >> 4;

    // XCD swizzle: 512 blocks, 8 XCDs -> 2 cat-panels x 32 by per XCD
    const int bid = blockIdx.x;
    const int bxc = (bid & 7) * 2 + (bid >> 8);   // cat-tile [0,16)
    const int by  = (bid >> 3) & 31;              // m-tile   [0,32)
    const int m0   = by * 256;
    const int cat0 = bxc * 256;
    const int n0   = bxc * 64;

    // staging: panel [128][32] = 8KB = 512thr x 16B, 1 load/thread.
    const int srow = tid >> 2;
    const int sgch = (tid & 3) ^ ((tid >> 3) & 3);
    const __bf16* Ags = A  + (size_t)(m0   + srow) * KDIM + sgch * 8;
    const __bf16* Bgs = Wt + (size_t)(cat0 + srow) * KDIM + sgch * 8;
    char* ldsw = smem + wave * 1024;

#define STG(o, h, kt, b) do { \
    const __bf16* gp_ = ((o) ? Bgs : Ags) + (size_t)(h) * 128 * KDIM + (kt) * 64; \
    char* lp_ = ldsw + (b) * 65536 + (o) * 32768 + (h) * 16384; \
    async_cp16(gp_,      lp_); \
    async_cp16(gp_ + 32, lp_ + 8192); \
} while (0)

    // fragment read offsets: row r, k-chunk c -> byte r*64 + (c^((r>>1)&3))*16
    const int swz   = (quad ^ ((l15 >> 1) & 3)) * 16;
    const int abase = wm * 16384 + l15 * 64 + swz;
    const int bbase = 32768 + (wn >> 1) * 16384 + ((wn & 1) * 64 + l15) * 64 + swz;

    f32x4 acc[8][4];
    #pragma unroll
    for (int i = 0; i < 8; ++i)
        #pragma unroll
        for (int j = 0; j < 4; ++j) acc[i][j] = (f32x4){0.f, 0.f, 0.f, 0.f};

    bf16x8 af[4][2];   // current m-quadrant (4 frags x 2 ks)
    bf16x8 bf[4][2];   // all 4 n-frags x 2 ks

    auto LDA = [&](int mh, int bufb) {
        const char* p = smem + bufb + abase + mh * 4096;
        #pragma unroll
        for (int m = 0; m < 4; ++m) {
            af[m][0] = *(const bf16x8*)(p + m * 1024);
            af[m][1] = *(const bf16x8*)(p + m * 1024 + 8192);
        }
    };
    auto LDB = [&](int nh, int bufb) {
        const char* p = smem + bufb + bbase + nh * 2048;
        #pragma unroll
        for (int n = 0; n < 2; ++n) {
            bf[nh * 2 + n][0] = *(const bf16x8*)(p + n * 1024);
            bf[nh * 2 + n][1] = *(const bf16x8*)(p + n * 1024 + 8192);
        }
    };
    auto MMA = [&](int mh, int nh) {
        #pragma unroll
        for (int m = 0; m < 4; ++m)
            #pragma unroll
            for (int n = 0; n < 2; ++n) {
                acc[mh * 4 + m][nh * 2 + n] = __builtin_amdgcn_mfma_f32_16x16x32_bf16(
                    af[m][0], bf[nh * 2 + n][0], acc[mh * 4 + m][nh * 2 + n], 0, 0, 0);
                acc[mh * 4 + m][nh * 2 + n] = __builtin_amdgcn_mfma_f32_16x16x32_bf16(
                    af[m][1], bf[nh * 2 + n][1], acc[mh * 4 + m][nh * 2 + n], 0, 0, 0);
            }
    };

    // ---- prologue: tile0 fully + tile1 h0 halves; keep tile1-h0 in flight
    STG(0, 0, 0, 0); STG(1, 0, 0, 0); STG(0, 1, 0, 0); STG(1, 1, 0, 0);
    STG(0, 0, 1, 1); STG(1, 0, 1, 1);
    asm volatile("s_waitcnt vmcnt(4)" ::: "memory");   // tile0 landed
    BARM;

    #pragma unroll 2
    for (int t = 0; t < NT; ++t) {
        const int b    = t & 1;
        const int bufb = b * 65536;
        // phase 0: quadrant (mh0, nh0); stage (t+1) A-h1 -> other buf
        LDA(0, bufb); LDB(0, bufb);
        if (t + 1 < NT) STG(0, 1, t + 1, b ^ 1);
        BARM; asm volatile("s_waitcnt lgkmcnt(0)" ::: "memory");
        __builtin_amdgcn_s_setprio(1); MMA(0, 0); __builtin_amdgcn_s_setprio(0);
        BARM;
        // phase 1: (mh0, nh1); stage (t+1) B-h1
        LDB(1, bufb);
        if (t + 1 < NT) STG(1, 1, t + 1, b ^ 1);
        BARM; asm volatile("s_waitcnt lgkmcnt(0)" ::: "memory");
        __builtin_amdgcn_s_setprio(1); MMA(0, 1); __builtin_amdgcn_s_setprio(0);
        BARM;
        // phase 2: (mh1, nh0); no stage
        LDA(1, bufb);
        BARM; asm volatile("s_waitcnt lgkmcnt(0)" ::: "memory");
        __builtin_amdgcn_s_setprio(1); MMA(1, 0); __builtin_amdgcn_s_setprio(0);
        BARM;
        // phase 3: (mh1, nh1); stage (t+2) h0 halves into cur buf (now free);
        // boundary vmcnt BEFORE barrier -> publishes tile t+1 cross-wave.
        if (t + 2 < NT) { STG(0, 0, t + 2, b); STG(1, 0, t + 2, b); }
        if (t < NT - 2) { asm volatile("s_waitcnt vmcnt(4)" ::: "memory"); }
        else            { asm volatile("s_waitcnt vmcnt(0)" ::: "memory"); }
        BARM;
        __builtin_amdgcn_s_setprio(1); MMA(1, 1); __builtin_amdgcn_s_setprio(0);
        BARM;
    }

    // ---- epilogue: 4 passes of 64 m-rows; Ep[64][258] f32 (66KB, 2-way banks)
    float* Ep = (float*)smem;
    const int nn = tid & 63;
    const float bvi = b_i[n0 + nn], bvf = b_f[n0 + nn];
    const float bvo = b_o[n0 + nn], bvg = b_g[n0 + nn];
    int colW[4];
    #pragma unroll
    for (int nt = 0; nt < 4; ++nt)
        colW[nt] = ((wn & 1) * 2 + (nt >> 1)) * 64 + (wn >> 1) * 32 + (nt & 1) * 16 + l15;

    #pragma unroll
    for (int ch = 0; ch < 4; ++ch) {
        __syncthreads();
        if (wm == (ch >> 1)) {
            #pragma unroll
            for (int mi = 0; mi < 4; ++mi) {
                const int mt = (ch & 1) * 4 + mi;
                #pragma unroll
                for (int nt = 0; nt < 4; ++nt)
                    #pragma unroll
                    for (int r = 0; r < 4; ++r)
                        Ep[(mi * 16 + quad * 4 + r) * 258 + colW[nt]] = acc[mt][nt][r];
            }
        }
        __syncthreads();
        #pragma unroll
        for (int e = 0; e < 8; ++e) {
            const int row = e * 8 + wave;
            const float gi = sigm(Ep[row * 258 + nn] + bvi);
            const float gf = sigm(Ep[row * 258 + 64 + nn] + bvf);
            const float go = sigm(Ep[row * 258 + 128 + nn] + bvo);
            const float gg = tanh_fast(Ep[row * 258 + 192 + nn] + bvg);
            const size_t pos = (size_t)(m0 + ch * 64 + row) * NDIM + n0 + nn;
            const float cp = c_prev[pos];
            const float cv = gf * cp + gi * gg;
            out[pos] = go * tanh_fast(cv);                 // h
            out[(size_t)BDIM * NDIM + pos] = cv;           // c
        }
    }
#undef STG
}

extern "C" void kernel_launch(void* const* d_in, const int* in_sizes, int n_in,
                              void* d_out, int out_size, void* d_ws, size_t ws_size,
                              hipStream_t stream) {
    const float* Z  = (const float*)d_in[0];
    const float* H  = (const float*)d_in[1];
    const float* Cp = (const float*)d_in[2];
    const float* Wi = (const float*)d_in[3];
    const float* bi = (const float*)d_in[4];
    const float* Wf = (const float*)d_in[5];
    const float* bf = (const float*)d_in[6];
    const float* Wo = (const float*)d_in[7];
    const float* bo = (const float*)d_in[8];
    const float* Wg = (const float*)d_in[9];
    const float* bg = (const float*)d_in[10];

    __bf16* Acomb = (__bf16*)d_ws;                              // 32 MB
    __bf16* Wtp   = (__bf16*)((char*)d_ws + (size_t)33554432);  // 16 MB

    static bool cfg = false;
    if (!cfg) {
        hipFuncSetAttribute(reinterpret_cast<const void*>(lstm_gemm_kernel),
                            hipFuncAttributeMaxDynamicSharedMemorySize, 131072);
        cfg = true;
    }

    prep_kernel<<<4096, 256, 0, stream>>>(Z, H, Wi, Wf, Wo, Wg, Acomb, Wtp);
    lstm_gemm_kernel<<<512, 512, 131072, stream>>>(
        Acomb, Wtp, bi, bf, bo, bg, Cp, (float*)d_out);
}

// Round 10
// 303.921 us; speedup vs baseline: 1.5356x; 1.0405x over previous
//
#include <hip/hip_runtime.h>

// LSTM cell fused, round 13: R12 GEMM with three orthogonal micro-fixes.
// (1) Panel-fast block order: same-XCD consecutive blocks share the A m-slice
//     (L2-hit) while both Wt panels stay resident -- attacks the measured
//     3.6x HBM over-fetch (287MB vs 80MB unique).
// (2) Per-chunk c_prev register prefetch (8 regs, nontemporal): HBM latency
//     hides under the epilogue's LDS writes + barriers.
// (3) Nontemporal h/c stores: write-once streams stop evicting A/Wt from L2.
// Prep unchanged (3 rewrites proved invariance at ~50us).

#define BDIM 8192
#define KDIM 2048
#define NDIM 1024
#define NCAT 4096
#define NT   32      // K-tiles of 64

typedef __bf16 bf16x8 __attribute__((ext_vector_type(8)));
typedef float  f32x4  __attribute__((ext_vector_type(4)));

__device__ __forceinline__ void async_cp16(const void* g, void* l) {
    __builtin_amdgcn_global_load_lds((__attribute__((address_space(1))) void*)g,
                                     (__attribute__((address_space(3))) void*)l,
                                     16, 0, 0);
}

__device__ __forceinline__ float sigm(float x) { return 1.f / (1.f + __expf(-x)); }
__device__ __forceinline__ float tanh_fast(float x) { return 1.f - 2.f / (1.f + __expf(2.f * x)); }

#define BARM asm volatile("s_barrier" ::: "memory")

// ---------------- prep v3 (R12): transpose-first, fat pack blocks ----------
__global__ __launch_bounds__(256)
void prep_kernel(const float* __restrict__ Z, const float* __restrict__ H,
                 const float* __restrict__ Wi, const float* __restrict__ Wf,
                 const float* __restrict__ Wo, const float* __restrict__ Wg,
                 __bf16* __restrict__ A, __bf16* __restrict__ Wt) {
    __shared__ float t[64][65];
    const int bid = blockIdx.x;
    const int tid = threadIdx.x;

    if (bid < 2048) {
        const int g   = bid >> 9;
        const int rem = bid & 511;
        const int k0  = (rem & 31) * 64;
        const int n0  = (rem >> 5) * 64;
        const float* W = (g == 0) ? Wi : (g == 1) ? Wf : (g == 2) ? Wo : Wg;

        const int c4 = tid & 15, r0 = tid >> 4;
        #pragma unroll
        for (int it = 0; it < 4; ++it) {
            const int r = r0 + it * 16;
            float4 v = ((const float4*)W)[(size_t)(k0 + r) * 256 + (n0 >> 2) + c4];
            t[r][c4 * 4 + 0] = v.x;
            t[r][c4 * 4 + 1] = v.y;
            t[r][c4 * 4 + 2] = v.z;
            t[r][c4 * 4 + 3] = v.w;
        }
        __syncthreads();

        const int kc = tid & 7, nn0 = tid >> 3;
        #pragma unroll
        for (int j = 0; j < 2; ++j) {
            const int n    = nn0 + j * 32;
            const int ncat = n0 + n;
            const size_t outRow = (size_t)(ncat >> 5) * 128 + g * 32 + (ncat & 31);
            bf16x8 o;
            #pragma unroll
            for (int kk = 0; kk < 8; ++kk) o[kk] = (__bf16)t[kc * 8 + kk][n];
            *(bf16x8*)(Wt + outRow * KDIM + k0 + kc * 8) = o;
        }
    } else {
        const bool isZ = (bid < 3072);
        const int base = (bid - (isZ ? 2048 : 3072)) * 1024;
        const float* src = isZ ? Z : H;
        #pragma unroll
        for (int it = 0; it < 4; ++it) {
            const int u   = base + it * 256 + tid;
            const int row = u >> 7;
            const int q8  = u & 127;
            const float4* p = (const float4*)src + ((size_t)row << 8) + q8 * 2;
            float4 v0 = p[0], v1 = p[1];
            bf16x8 o = { (__bf16)v0.x, (__bf16)v0.y, (__bf16)v0.z, (__bf16)v0.w,
                         (__bf16)v1.x, (__bf16)v1.y, (__bf16)v1.z, (__bf16)v1.w };
            const int col8 = isZ ? q8 : (q8 + 128);
            ((bf16x8*)A)[(size_t)row * 256 + col8] = o;
        }
    }
}

// ---------------- 256x256 8-phase GEMM + fused LSTM epilogue ---------------
__global__ __launch_bounds__(512, 2)
void lstm_gemm_kernel(const __bf16* __restrict__ A, const __bf16* __restrict__ Wt,
                      const float* __restrict__ b_i, const float* __restrict__ b_f,
                      const float* __restrict__ b_o, const float* __restrict__ b_g,
                      const float* __restrict__ c_prev, float* __restrict__ out) {
    extern __shared__ char smem[];   // 128KB: buf{0,1} x { A 2x16KB | B 2x16KB }

    const int tid  = threadIdx.x;
    const int wave = tid >> 6;
    const int lane = tid & 63;
    const int wm   = wave >> 2;      // 0..1  (m half: 128 rows each)
    const int wn   = wave & 3;       // 0..3  (64 cat cols each)
    const int l15  = lane & 15;
    const int quad = lane >> 4;

    // XCD swizzle, PANEL-FAST: same-XCD consecutive blocks share the m-tile
    // (A-slice L2-hit) while alternating the XCD's 2 resident Wt panels.
    const int bid   = blockIdx.x;
    const int xcd   = bid & 7;
    const int panel = (bid >> 3) & 1;
    const int by    = bid >> 4;                   // m-tile [0,32)
    const int bxc   = xcd * 2 + panel;            // cat-tile [0,16)
    const int m0   = by * 256;
    const int cat0 = bxc * 256;
    const int n0   = bxc * 64;

    // staging: panel [128][32] = 8KB = 512thr x 16B, 1 load/thread.
    const int srow = tid >> 2;
    const int sgch = (tid & 3) ^ ((tid >> 3) & 3);
    const __bf16* Ags = A  + (size_t)(m0   + srow) * KDIM + sgch * 8;
    const __bf16* Bgs = Wt + (size_t)(cat0 + srow) * KDIM + sgch * 8;
    char* ldsw = smem + wave * 1024;

#define STG(o, h, kt, b) do { \
    const __bf16* gp_ = ((o) ? Bgs : Ags) + (size_t)(h) * 128 * KDIM + (kt) * 64; \
    char* lp_ = ldsw + (b) * 65536 + (o) * 32768 + (h) * 16384; \
    async_cp16(gp_,      lp_); \
    async_cp16(gp_ + 32, lp_ + 8192); \
} while (0)

    // fragment read offsets: row r, k-chunk c -> byte r*64 + (c^((r>>1)&3))*16
    const int swz   = (quad ^ ((l15 >> 1) & 3)) * 16;
    const int abase = wm * 16384 + l15 * 64 + swz;
    const int bbase = 32768 + (wn >> 1) * 16384 + ((wn & 1) * 64 + l15) * 64 + swz;

    f32x4 acc[8][4];
    #pragma unroll
    for (int i = 0; i < 8; ++i)
        #pragma unroll
        for (int j = 0; j < 4; ++j) acc[i][j] = (f32x4){0.f, 0.f, 0.f, 0.f};

    bf16x8 af[4][2];   // current m-quadrant (4 frags x 2 ks)
    bf16x8 bf[4][2];   // all 4 n-frags x 2 ks

    auto LDA = [&](int mh, int bufb) {
        const char* p = smem + bufb + abase + mh * 4096;
        #pragma unroll
        for (int m = 0; m < 4; ++m) {
            af[m][0] = *(const bf16x8*)(p + m * 1024);
            af[m][1] = *(const bf16x8*)(p + m * 1024 + 8192);
        }
    };
    auto LDB = [&](int nh, int bufb) {
        const char* p = smem + bufb + bbase + nh * 2048;
        #pragma unroll
        for (int n = 0; n < 2; ++n) {
            bf[nh * 2 + n][0] = *(const bf16x8*)(p + n * 1024);
            bf[nh * 2 + n][1] = *(const bf16x8*)(p + n * 1024 + 8192);
        }
    };
    auto MMA = [&](int mh, int nh) {
        #pragma unroll
        for (int m = 0; m < 4; ++m)
            #pragma unroll
            for (int n = 0; n < 2; ++n) {
                acc[mh * 4 + m][nh * 2 + n] = __builtin_amdgcn_mfma_f32_16x16x32_bf16(
                    af[m][0], bf[nh * 2 + n][0], acc[mh * 4 + m][nh * 2 + n], 0, 0, 0);
                acc[mh * 4 + m][nh * 2 + n] = __builtin_amdgcn_mfma_f32_16x16x32_bf16(
                    af[m][1], bf[nh * 2 + n][1], acc[mh * 4 + m][nh * 2 + n], 0, 0, 0);
            }
    };

    // ---- prologue: tile0 fully + tile1 h0 halves; keep tile1-h0 in flight
    STG(0, 0, 0, 0); STG(1, 0, 0, 0); STG(0, 1, 0, 0); STG(1, 1, 0, 0);
    STG(0, 0, 1, 1); STG(1, 0, 1, 1);
    asm volatile("s_waitcnt vmcnt(4)" ::: "memory");   // tile0 landed
    BARM;

    #pragma unroll 2
    for (int t = 0; t < NT; ++t) {
        const int b    = t & 1;
        const int bufb = b * 65536;
        // phase 0: quadrant (mh0, nh0); stage (t+1) A-h1 -> other buf
        LDA(0, bufb); LDB(0, bufb);
        if (t + 1 < NT) STG(0, 1, t + 1, b ^ 1);
        BARM; asm volatile("s_waitcnt lgkmcnt(0)" ::: "memory");
        __builtin_amdgcn_s_setprio(1); MMA(0, 0); __builtin_amdgcn_s_setprio(0);
        BARM;
        // phase 1: (mh0, nh1); stage (t+1) B-h1
        LDB(1, bufb);
        if (t + 1 < NT) STG(1, 1, t + 1, b ^ 1);
        BARM; asm volatile("s_waitcnt lgkmcnt(0)" ::: "memory");
        __builtin_amdgcn_s_setprio(1); MMA(0, 1); __builtin_amdgcn_s_setprio(0);
        BARM;
        // phase 2: (mh1, nh0); no stage
        LDA(1, bufb);
        BARM; asm volatile("s_waitcnt lgkmcnt(0)" ::: "memory");
        __builtin_amdgcn_s_setprio(1); MMA(1, 0); __builtin_amdgcn_s_setprio(0);
        BARM;
        // phase 3: (mh1, nh1); stage (t+2) h0 halves; counted vmcnt publishes t+1
        if (t + 2 < NT) { STG(0, 0, t + 2, b); STG(1, 0, t + 2, b); }
        if (t < NT - 2) { asm volatile("s_waitcnt vmcnt(4)" ::: "memory"); }
        else            { asm volatile("s_waitcnt vmcnt(0)" ::: "memory"); }
        BARM;
        __builtin_amdgcn_s_setprio(1); MMA(1, 1); __builtin_amdgcn_s_setprio(0);
        BARM;
    }

    // ---- epilogue: 4 passes of 64 m-rows; Ep[64][258] f32 (66KB) ----
    float* Ep = (float*)smem;
    const int nn = tid & 63;
    const float bvi = b_i[n0 + nn], bvf = b_f[n0 + nn];
    const float bvo = b_o[n0 + nn], bvg = b_g[n0 + nn];
    int colW[4];
    #pragma unroll
    for (int nt = 0; nt < 4; ++nt)
        colW[nt] = ((wn & 1) * 2 + (nt >> 1)) * 64 + (wn >> 1) * 32 + (nt & 1) * 16 + l15;

    #pragma unroll
    for (int ch = 0; ch < 4; ++ch) {
        // prefetch this chunk's c_prev (nontemporal, read-once); latency
        // hides under the Ep LDS writes + 2 barriers below.
        float cpv[8];
        #pragma unroll
        for (int e = 0; e < 8; ++e) {
            const int row = e * 8 + wave;
            cpv[e] = __builtin_nontemporal_load(
                &c_prev[(size_t)(m0 + ch * 64 + row) * NDIM + n0 + nn]);
        }
        __syncthreads();
        if (wm == (ch >> 1)) {
            #pragma unroll
            for (int mi = 0; mi < 4; ++mi) {
                const int mt = (ch & 1) * 4 + mi;
                #pragma unroll
                for (int nt = 0; nt < 4; ++nt)
                    #pragma unroll
                    for (int r = 0; r < 4; ++r)
                        Ep[(mi * 16 + quad * 4 + r) * 258 + colW[nt]] = acc[mt][nt][r];
            }
        }
        __syncthreads();
        #pragma unroll
        for (int e = 0; e < 8; ++e) {
            const int row = e * 8 + wave;
            const float gi = sigm(Ep[row * 258 + nn] + bvi);
            const float gf = sigm(Ep[row * 258 + 64 + nn] + bvf);
            const float go = sigm(Ep[row * 258 + 128 + nn] + bvo);
            const float gg = tanh_fast(Ep[row * 258 + 192 + nn] + bvg);
            const size_t pos = (size_t)(m0 + ch * 64 + row) * NDIM + n0 + nn;
            const float cv = gf * cpv[e] + gi * gg;
            __builtin_nontemporal_store(go * tanh_fast(cv), &out[pos]);          // h
            __builtin_nontemporal_store(cv, &out[(size_t)BDIM * NDIM + pos]);    // c
        }
    }
#undef STG
}

extern "C" void kernel_launch(void* const* d_in, const int* in_sizes, int n_in,
                              void* d_out, int out_size, void* d_ws, size_t ws_size,
                              hipStream_t stream) {
    const float* Z  = (const float*)d_in[0];
    const float* H  = (const float*)d_in[1];
    const float* Cp = (const float*)d_in[2];
    const float* Wi = (const float*)d_in[3];
    const float* bi = (const float*)d_in[4];
    const float* Wf = (const float*)d_in[5];
    const float* bf = (const float*)d_in[6];
    const float* Wo = (const float*)d_in[7];
    const float* bo = (const float*)d_in[8];
    const float* Wg = (const float*)d_in[9];
    const float* bg = (const float*)d_in[10];

    __bf16* Acomb = (__bf16*)d_ws;                              // 32 MB
    __bf16* Wtp   = (__bf16*)((char*)d_ws + (size_t)33554432);  // 16 MB

    static bool cfg = false;
    if (!cfg) {
        hipFuncSetAttribute(reinterpret_cast<const void*>(lstm_gemm_kernel),
                            hipFuncAttributeMaxDynamicSharedMemorySize, 131072);
        cfg = true;
    }

    prep_kernel<<<4096, 256, 0, stream>>>(Z, H, Wi, Wf, Wo, Wg, Acomb, Wtp);
    lstm_gemm_kernel<<<512, 512, 131072, stream>>>(
        Acomb, Wtp, bi, bf, bo, bg, Cp, (float*)d_out);
}